// Round 9
// baseline (29524.466 us; speedup 1.0000x reference)
//
#include <hip/hip_runtime.h>
#include <math.h>

// Problem constants (fixed by reference)
#define Bb      16
#define Nn      15
#define Tt      50
#define Gg      4840
#define G2c     9680        // 2*G
#define BTc     800         // B*T
#define NNc     30          // 2*N
#define NITER   50
#define NRANGES 40

// fused-solver geometry (r6 shape + register double-buffered prefetch)
#define G64     76          // 64-g chunks (76*64 = 4864 >= 4840)
#define GP      4864        // padded grid points
#define CPB     4           // columns per block
#define NB      200         // blocks = 800 columns / 4
#define TPB     512         // 2 sets x 256 threads; each set owns 2 columns

// ---------------- setup kernels ----------------

// Packed A: Ac[chunk*2048 + q*256 + l*4 + j], j=0..3 ->
//   (Ar[2q][g], Ai[2q][g], Ar[2q+1][g], Ai[2q+1][g]), g = chunk*64+l.
// q=7, j>=2 -> k=15 pad = 0. Lane l reads one float4 -> wave reads 1KB contiguous.
__global__ void repack_a_kernel(const float* __restrict__ Ar, const float* __restrict__ Ai,
                                float* __restrict__ Ac) {
    int idx = blockIdx.x * 256 + threadIdx.x;
    if (idx >= G64 * 2048) return;
    int chunk = idx >> 11, rem = idx & 2047;
    int q = rem >> 8, rem2 = rem & 255;
    int l = rem2 >> 2, j = rem2 & 3;
    int g = chunk * 64 + l;
    int k = 2 * q + (j >> 1);
    float v = 0.f;
    if (g < Gg && k < Nn) v = (j & 1) ? Ai[k * Gg + g] : Ar[k * Gg + g];
    Ac[idx] = v;
}

__device__ __forceinline__ float a_elem(const float* __restrict__ Ar,
                                        const float* __restrict__ Ai,
                                        int n, int g2) {
    if (g2 < Gg) {
        return (n < Nn) ? Ar[n * Gg + g2] : Ai[(n - Nn) * Gg + g2];
    } else {
        int g = g2 - Gg;
        return (n < Nn) ? -Ai[n * Gg + g] : Ar[(n - Nn) * Gg + g];
    }
}

// M30[i][j] = sum_g2 A[i][g2]*A[j][g2]  (double accumulation), coalesced over g2
__global__ void gram_kernel(const float* __restrict__ Ar, const float* __restrict__ Ai,
                            double* __restrict__ M30) {
    int i = blockIdx.x / NNc, j = blockIdx.x % NNc;
    double acc = 0.0;
    for (int g2 = threadIdx.x; g2 < G2c; g2 += 256)
        acc += (double)a_elem(Ar, Ai, i, g2) * (double)a_elem(Ar, Ai, j, g2);
    __shared__ double red[256];
    red[threadIdx.x] = acc;
    __syncthreads();
    for (int s = 128; s > 0; s >>= 1) {
        if (threadIdx.x < s) red[threadIdx.x] += red[threadIdx.x + s];
        __syncthreads();
    }
    if (threadIdx.x == 0) M30[i * NNc + j] = red[0];
}

// Largest eigenvalue of the 30x30 Gram via 10 LDS matrix squarings (M^1024),
// dominant eigvec = column 0, then Rayleigh with original M. fp64, 1024 threads.
__global__ void step_kernel(const double* __restrict__ M30, float* __restrict__ st) {
    __shared__ double M0[NNc][NNc];
    __shared__ double Mc[NNc][NNc];
    __shared__ double s[1024];
    int tid = threadIdx.x;
    int i = tid / NNc, j = tid - i * NNc;
    bool act = tid < NNc * NNc;
    if (act) M0[i][j] = M30[tid];
    __syncthreads();
    s[tid] = act ? fabs(M0[i][j]) : 0.0;
    __syncthreads();
    for (int o = 512; o; o >>= 1) {
        if (tid < o) s[tid] = fmax(s[tid], s[tid + o]);
        __syncthreads();
    }
    double mx = s[0];
    __syncthreads();
    if (act) Mc[i][j] = M0[i][j] / mx;
    __syncthreads();
    for (int sq = 0; sq < 10; sq++) {
        double t = 0.0;
        if (act) {
            for (int k = 0; k < NNc; k++) t += Mc[i][k] * Mc[k][j];
        }
        s[tid] = act ? fabs(t) : 0.0;
        __syncthreads();
        for (int o = 512; o; o >>= 1) {
            if (tid < o) s[tid] = fmax(s[tid], s[tid + o]);
            __syncthreads();
        }
        double m2 = s[0];
        __syncthreads();
        if (act) Mc[i][j] = t / m2;
        __syncthreads();
    }
    s[tid] = act ? Mc[i][0] * M0[i][j] * Mc[j][0] : 0.0;
    __syncthreads();
    for (int o = 512; o; o >>= 1) {
        if (tid < o) s[tid] += s[tid + o];
        __syncthreads();
    }
    double num = s[0];
    __syncthreads();
    s[tid] = (tid < NNc) ? Mc[tid][0] * Mc[tid][0] : 0.0;
    __syncthreads();
    for (int o = 512; o; o >>= 1) {
        if (tid < o) s[tid] += s[tid + o];
        __syncthreads();
    }
    double den = s[0];
    if (tid == 0) {
        double lam = num / den;              // sigma_max(A)^2
        double step = (double)NNc / lam;     // 1 / (lam/30)
        st[0] = (float)step;
        st[1] = (float)(0.01 * step);        // MU * step
        st[2] = (float)(step / 30.0);        // folded scale for Aty and Ax
    }
}

// Packed Aty: AtyP[(bt>>1)*GP + g] is a float4 =
//   (re(col even), im(col even), re(col odd), im(col odd)), scaled by step/30.
__global__ void atys_kernel(const float* __restrict__ Ar, const float* __restrict__ Ai,
                            const float* __restrict__ yr, const float* __restrict__ yi,
                            const float* __restrict__ st, float* __restrict__ AtyP) {
    int bt = blockIdx.x;
    int b = bt / Tt, t = bt - b * Tt;
    int pair = bt >> 1, half = bt & 1;
    __shared__ float ysr[Nn], ysi[Nn];
    int tid = threadIdx.x;
    if (tid < Nn) {
        float s2 = st[2];
        ysr[tid] = s2 * yr[(b * Nn + tid) * Tt + t];
        ysi[tid] = s2 * yi[(b * Nn + tid) * Tt + t];
    }
    __syncthreads();
    float* base = AtyP + ((size_t)pair * GP) * 4 + half * 2;
    for (int g = tid; g < GP; g += 256) {
        float accR = 0.f, accI = 0.f;
        if (g < Gg) {
#pragma unroll
            for (int k = 0; k < Nn; k++) {
                float a = Ar[k * Gg + g], ci = Ai[k * Gg + g];
                accR = fmaf(a, ysr[k], accR);
                accR = fmaf(ci, ysi[k], accR);
                accI = fmaf(-ci, ysr[k], accI);
                accI = fmaf(a, ysi[k], accI);
            }
        }
        float2* p = (float2*)(base + (size_t)g * 4);
        *p = make_float2(accR, accI);
    }
}

// ---------------- fused ISTA solver ----------------
// r6 geometry: block owns 4 columns; 2 sets x 256 threads, each set owns 2
// columns. NEW: __launch_bounds__(512,1) frees the allocator up to 256 VGPR
// (occupancy is LDS-bound at 1 block/CU = 2 waves/SIMD regardless), enabling
// a register double-buffer: step n+1's A-block + Aty load while step n's
// 240 FMAs execute — hides the per-step L2 latency that capped r6 at 48%.
__global__ __launch_bounds__(TPB, 1) void ista_kernel(
    const float4* __restrict__ Ac4, const float4* __restrict__ AtyP4,
    const float* __restrict__ st, float* __restrict__ Xg,
    float* __restrict__ norms_g) {
    __shared__ float Xli[CPB][GP * 2];   // 155,648 B, [c][g][re,im]
    __shared__ float red[8][64];
    __shared__ float axb[CPB][32];
    int tid = threadIdx.x;
    int sset = tid >> 8;          // 0/1
    int l256 = tid & 255;
    int wsub = (tid >> 6) & 3;    // wave within set, 0..3
    int lane = tid & 63;
    int wv = tid >> 6;            // wave 0..7
    int c0 = 2 * sset, c1 = c0 + 1;
    int b4 = blockIdx.x;
    float thr = st[1], st2 = st[2];

    for (int k = tid; k < CPB * GP * 2; k += TPB) ((float*)Xli)[k] = 0.f;
    if (tid < CPB * 32) ((float*)axb)[tid] = 0.f;
    __syncthreads();

    const float4* atyp = AtyP4 + (size_t)(b4 * 2 + sset) * GP;

    for (int it = 0; it < NITER; it++) {
        float ax0[NNc], ax1[NNc];
#pragma unroll
        for (int n = 0; n < NNc; n++) { ax0[n] = axb[c0][n]; ax1[n] = axb[c1][n]; }
        float aR0[Nn], aI0[Nn], aR1[Nn], aI1[Nn];
#pragma unroll
        for (int k = 0; k < Nn; k++) { aR0[k] = 0.f; aI0[k] = 0.f; aR1[k] = 0.f; aI1[k] = 0.f; }

        // prologue: prefetch step 0 (chunk = wsub)
        float4 aqA[8];
        float4 tyA;
        {
            const float4* pA = Ac4 + (size_t)wsub * 512 + lane;
#pragma unroll
            for (int q = 0; q < 8; q++) aqA[q] = pA[q * 64];
            tyA = atyp[l256];
        }

#pragma unroll 2
        for (int stp = 0; stp < 19; stp++) {
            int g = stp * 256 + l256;
            // prefetch step n+1 while computing step n
            float4 aqB[8];
            float4 tyB;
            if (stp < 18) {
                int chunk = ((stp + 1) << 2) + wsub;
                const float4* pB = Ac4 + (size_t)chunk * 512 + lane;
#pragma unroll
                for (int q = 0; q < 8; q++) aqB[q] = pB[q * 64];
                tyB = atyp[g + 256];
            }
            float2 x0 = *(const float2*)(&Xli[c0][2 * g]);
            float2 x1 = *(const float2*)(&Xli[c1][2 * g]);
            // v = x + step*Aty - step/30 * A^T(Ax)
            float vr0 = x0.x + tyA.x, vi0 = x0.y + tyA.y;
            float vr1 = x1.x + tyA.z, vi1 = x1.y + tyA.w;
#pragma unroll
            for (int q = 0; q < 7; q++) {
                float4 a = aqA[q];
                int k0 = 2 * q, k1 = 2 * q + 1;
                vr0 = fmaf(-a.x, ax0[k0], vr0); vr0 = fmaf(-a.y, ax0[Nn + k0], vr0);
                vi0 = fmaf( a.y, ax0[k0], vi0); vi0 = fmaf(-a.x, ax0[Nn + k0], vi0);
                vr0 = fmaf(-a.z, ax0[k1], vr0); vr0 = fmaf(-a.w, ax0[Nn + k1], vr0);
                vi0 = fmaf( a.w, ax0[k1], vi0); vi0 = fmaf(-a.z, ax0[Nn + k1], vi0);
                vr1 = fmaf(-a.x, ax1[k0], vr1); vr1 = fmaf(-a.y, ax1[Nn + k0], vr1);
                vi1 = fmaf( a.y, ax1[k0], vi1); vi1 = fmaf(-a.x, ax1[Nn + k0], vi1);
                vr1 = fmaf(-a.z, ax1[k1], vr1); vr1 = fmaf(-a.w, ax1[Nn + k1], vr1);
                vi1 = fmaf( a.w, ax1[k1], vi1); vi1 = fmaf(-a.z, ax1[Nn + k1], vi1);
            }
            {   // tail k = 14 (aqA[7].x/.y; .z/.w are zero pad)
                float4 a = aqA[7];
                vr0 = fmaf(-a.x, ax0[14], vr0); vr0 = fmaf(-a.y, ax0[29], vr0);
                vi0 = fmaf( a.y, ax0[14], vi0); vi0 = fmaf(-a.x, ax0[29], vi0);
                vr1 = fmaf(-a.x, ax1[14], vr1); vr1 = fmaf(-a.y, ax1[29], vr1);
                vi1 = fmaf( a.y, ax1[14], vi1); vi1 = fmaf(-a.x, ax1[29], vi1);
            }
            float m;
            m = fabsf(vr0) - thr; float xr0 = (m > 0.f) ? copysignf(m, vr0) : 0.f;
            m = fabsf(vi0) - thr; float xi0 = (m > 0.f) ? copysignf(m, vi0) : 0.f;
            m = fabsf(vr1) - thr; float xr1 = (m > 0.f) ? copysignf(m, vr1) : 0.f;
            m = fabsf(vi1) - thr; float xi1 = (m > 0.f) ? copysignf(m, vi1) : 0.f;
            *(float2*)(&Xli[c0][2 * g]) = make_float2(xr0, xi0);
            *(float2*)(&Xli[c1][2 * g]) = make_float2(xr1, xi1);
            // sparse accumulation: skip waves whose 64 g's are all-zero (exact)
            int nz = (xr0 != 0.f) | (xi0 != 0.f) | (xr1 != 0.f) | (xi1 != 0.f);
            if (__any(nz)) {
#pragma unroll
                for (int q = 0; q < 7; q++) {
                    float4 a = aqA[q];
                    int k0 = 2 * q, k1 = 2 * q + 1;
                    aR0[k0] = fmaf(a.x, xr0, aR0[k0]); aR0[k0] = fmaf(-a.y, xi0, aR0[k0]);
                    aI0[k0] = fmaf(a.y, xr0, aI0[k0]); aI0[k0] = fmaf( a.x, xi0, aI0[k0]);
                    aR0[k1] = fmaf(a.z, xr0, aR0[k1]); aR0[k1] = fmaf(-a.w, xi0, aR0[k1]);
                    aI0[k1] = fmaf(a.w, xr0, aI0[k1]); aI0[k1] = fmaf( a.z, xi0, aI0[k1]);
                    aR1[k0] = fmaf(a.x, xr1, aR1[k0]); aR1[k0] = fmaf(-a.y, xi1, aR1[k0]);
                    aI1[k0] = fmaf(a.y, xr1, aI1[k0]); aI1[k0] = fmaf( a.x, xi1, aI1[k0]);
                    aR1[k1] = fmaf(a.z, xr1, aR1[k1]); aR1[k1] = fmaf(-a.w, xi1, aR1[k1]);
                    aI1[k1] = fmaf(a.w, xr1, aI1[k1]); aI1[k1] = fmaf( a.z, xi1, aI1[k1]);
                }
                {
                    float4 a = aqA[7];
                    aR0[14] = fmaf(a.x, xr0, aR0[14]); aR0[14] = fmaf(-a.y, xi0, aR0[14]);
                    aI0[14] = fmaf(a.y, xr0, aI0[14]); aI0[14] = fmaf( a.x, xi0, aI0[14]);
                    aR1[14] = fmaf(a.x, xr1, aR1[14]); aR1[14] = fmaf(-a.y, xi1, aR1[14]);
                    aI1[14] = fmaf(a.y, xr1, aI1[14]); aI1[14] = fmaf( a.x, xi1, aI1[14]);
                }
            }
            if (stp < 18) {
#pragma unroll
                for (int q = 0; q < 8; q++) aqA[q] = aqB[q];
                tyA = tyB;
            }
        }
        if (it == NITER - 1) break;
        // wave-level butterfly reduce of the 60 accumulators
#pragma unroll
        for (int k = 0; k < Nn; k++) {
            for (int o = 32; o; o >>= 1) {
                aR0[k] += __shfl_xor(aR0[k], o);
                aI0[k] += __shfl_xor(aI0[k], o);
                aR1[k] += __shfl_xor(aR1[k], o);
                aI1[k] += __shfl_xor(aI1[k], o);
            }
        }
        if (lane == 0) {
#pragma unroll
            for (int k = 0; k < Nn; k++) {
                red[wv][k] = aR0[k];
                red[wv][Nn + k] = aI0[k];
                red[wv][30 + k] = aR1[k];
                red[wv][45 + k] = aI1[k];
            }
        }
        __syncthreads();
        if (tid < CPB * NNc) {
            int c = tid / NNc, n = tid - c * NNc;
            int s4 = (c >> 1) * 4, off = (c & 1) * 30 + n;
            axb[c][n] = st2 * (red[s4][off] + red[s4 + 1][off] +
                               red[s4 + 2][off] + red[s4 + 3][off]);
        }
        __syncthreads();
    }
    __syncthreads();

    // writeback X (layout Xg[bt][G2c]: real at g, imag at Gg+g) + column norms
    for (int c = 0; c < CPB; c++) {
        int bt = b4 * CPB + c;
        float na = 0.f;
        for (int g = tid; g < Gg; g += TPB) {
            float2 xv = *(const float2*)(&Xli[c][2 * g]);
            Xg[(size_t)bt * G2c + g] = xv.x;
            Xg[(size_t)bt * G2c + Gg + g] = xv.y;
            na += sqrtf(fmaf(xv.x, xv.x, fmaf(xv.y, xv.y, 1e-12f)));
        }
        for (int o = 32; o; o >>= 1) na += __shfl_xor(na, o);
        if (lane == 0) red[wv][c] = na;
    }
    __syncthreads();
    if (tid < CPB) {
        float s = 0.f;
        for (int w = 0; w < 8; w++) s += red[w][tid];
        norms_g[b4 * CPB + tid] = s;
    }
}

// ---------------- epilogue kernels ----------------

__global__ __launch_bounds__(832) void argmin_kernel(const float* __restrict__ norms_g,
                                                     int* __restrict__ midx) {
    __shared__ float norms[BTc];
    int tid = threadIdx.x;
    if (tid < BTc) norms[tid] = norms_g[tid];
    __syncthreads();
    if (tid < Bb) {
        float best = norms[tid * Tt];
        int bi = 0;
        for (int t = 1; t < Tt; t++) {
            float v = norms[tid * Tt + t];
            if (v < best) { best = v; bi = t; }
        }
        midx[tid] = bi;
    }
}

// s[b][g] = (1/16) * sum_j sqrt(x[g][b*50+tj]^2 + x[G+g][b*50+tj]^2 + 1e-12)
__global__ void s_kernel(const float* __restrict__ Xg, const int* __restrict__ midx,
                         float* __restrict__ out_s) {
    __shared__ int mi[Bb];
    if (threadIdx.x < Bb) mi[threadIdx.x] = midx[threadIdx.x];
    __syncthreads();
    int idx = blockIdx.x * 256 + threadIdx.x;
    if (idx >= Bb * Gg) return;
    int b = idx / Gg, g = idx - b * Gg;
    float acc = 0.f;
#pragma unroll
    for (int j = 0; j < Bb; j++) {
        int bt = b * Tt + mi[j];
        float xr = Xg[(size_t)bt * G2c + g];
        float xi = Xg[(size_t)bt * G2c + Gg + g];
        acc += sqrtf(fmaf(xr, xr, fmaf(xi, xi, 1e-12f)));
    }
    out_s[idx] = acc * (1.f / 16.f);
}

__device__ __forceinline__ bool better_pair(float v, int i, float bv, int bi) {
    return (v > bv) || (v == bv && i < bi);
}

// Stable top-2 per batch (lax.top_k semantics: descending, ties -> lower index)
__global__ void top2_kernel(const float* __restrict__ out_s, const float* __restrict__ angles,
                            const float* __restrict__ ranges, float* __restrict__ out) {
    int b = blockIdx.x, tid = threadIdx.x;
    const float* sb = out_s + (size_t)b * Gg;
    float v1 = -INFINITY, v2 = -INFINITY;
    int i1 = 0x7fffffff, i2 = 0x7fffffff;
    for (int g = tid; g < Gg; g += 256) {
        float v = sb[g];
        if (better_pair(v, g, v1, i1)) { v2 = v1; i2 = i1; v1 = v; i1 = g; }
        else if (better_pair(v, g, v2, i2)) { v2 = v; i2 = g; }
    }
    __shared__ float sv1[256], sv2[256];
    __shared__ int si1[256], si2[256];
    sv1[tid] = v1; si1[tid] = i1; sv2[tid] = v2; si2[tid] = i2;
    __syncthreads();
    for (int stp = 128; stp > 0; stp >>= 1) {
        if (tid < stp) {
            float a1 = sv1[tid], a2 = sv2[tid];
            int ai1 = si1[tid], ai2 = si2[tid];
            float b1 = sv1[tid + stp], b2 = sv2[tid + stp];
            int bi1 = si1[tid + stp], bi2 = si2[tid + stp];
            float n1, n2;
            int ni1, ni2;
            if (better_pair(b1, bi1, a1, ai1)) {
                n1 = b1; ni1 = bi1;
                if (better_pair(a1, ai1, b2, bi2)) { n2 = a1; ni2 = ai1; }
                else { n2 = b2; ni2 = bi2; }
            } else {
                n1 = a1; ni1 = ai1;
                if (better_pair(b1, bi1, a2, ai2)) { n2 = b1; ni2 = bi1; }
                else { n2 = a2; ni2 = ai2; }
            }
            sv1[tid] = n1; si1[tid] = ni1; sv2[tid] = n2; si2[tid] = ni2;
        }
        __syncthreads();
    }
    if (tid == 0) {
        int ia = si1[0], ib2 = si2[0];
        out[b * 2 + 0] = angles[ia / NRANGES];
        out[b * 2 + 1] = angles[ib2 / NRANGES];
        out[32 + b * 2 + 0] = ranges[ia % NRANGES];
        out[32 + b * 2 + 1] = ranges[ib2 % NRANGES];
    }
}

// ---------------- launch ----------------

extern "C" void kernel_launch(void* const* d_in, const int* in_sizes, int n_in,
                              void* d_out, int out_size, void* d_ws, size_t ws_size,
                              hipStream_t stream) {
    const float* yr = (const float*)d_in[0];      // [16,15,50]
    const float* yi = (const float*)d_in[1];      // [16,15,50]
    const float* Ar = (const float*)d_in[2];      // [15,4840]
    const float* Ai = (const float*)d_in[3];      // [15,4840]
    const float* angles = (const float*)d_in[4];  // [121]
    const float* ranges = (const float*)d_in[5];  // [40]
    float* out = (float*)d_out;                   // 32 doa + 32 rng + 77440 s
    float* w = (float*)d_ws;

    // workspace layout (floats), ~63 MB total; all float4 users 16B-aligned
    size_t oAc = 0;                                // 76*2048 = 155648
    size_t oM30 = oAc + (size_t)G64 * 2048;        // 900 doubles
    size_t oSt = oM30 + 1800;                      // 8
    size_t oAtyP = oSt + 8;                        // 400*4864*4 = 7782400 (ofs 157456, 16B-aligned)
    size_t oXg = oAtyP + (size_t)(BTc / 2) * GP * 4;  // 800*9680 = 7744000
    size_t oNrm = oXg + (size_t)BTc * G2c;         // 800
    size_t oMidx = oNrm + BTc;                     // 16 ints

    float* Ac = w + oAc;
    double* M30 = (double*)(w + oM30);
    float* st = w + oSt;
    float* AtyP = w + oAtyP;
    float* Xg = w + oXg;
    float* norms_g = w + oNrm;
    int* midx = (int*)(w + oMidx);

    repack_a_kernel<<<(G64 * 2048) / 256, 256, 0, stream>>>(Ar, Ai, Ac);
    gram_kernel<<<NNc * NNc, 256, 0, stream>>>(Ar, Ai, M30);
    step_kernel<<<1, 1024, 0, stream>>>(M30, st);
    atys_kernel<<<BTc, 256, 0, stream>>>(Ar, Ai, yr, yi, st, AtyP);

    ista_kernel<<<NB, TPB, 0, stream>>>((const float4*)Ac, (const float4*)AtyP,
                                        st, Xg, norms_g);

    argmin_kernel<<<1, 832, 0, stream>>>(norms_g, midx);
    s_kernel<<<(Bb * Gg + 255) / 256, 256, 0, stream>>>(Xg, midx, out + 64);
    top2_kernel<<<Bb, 256, 0, stream>>>(out + 64, angles, ranges, out);
}

// Round 11
// 1576.227 us; speedup vs baseline: 18.7311x; 18.7311x over previous
//
#include <hip/hip_runtime.h>
#include <math.h>

// Problem constants (fixed by reference)
#define Bb      16
#define Nn      15
#define Tt      50
#define Gg      4840
#define G2c     9680        // 2*G
#define BTc     800         // B*T
#define NNc     30          // 2*N
#define NITER   50
#define NRANGES 40

// fused-solver geometry (round-6 verified optimum: packed loads, fp32 X in LDS)
#define G64     76          // 64-g chunks (76*64 = 4864 >= 4840)
#define GP      4864        // padded grid points
#define CPB     4           // columns per block
#define NB      200         // blocks = 800 columns / 4
#define TPB     512         // 2 sets x 256 threads; each set owns 2 columns

// ---------------- setup kernels ----------------

// Packed A: Ac[chunk*2048 + q*256 + l*4 + j], j=0..3 ->
//   (Ar[2q][g], Ai[2q][g], Ar[2q+1][g], Ai[2q+1][g]), g = chunk*64+l.
// q=7, j>=2 -> k=15 pad = 0. Lane l reads one float4 -> wave reads 1KB contiguous.
__global__ void repack_a_kernel(const float* __restrict__ Ar, const float* __restrict__ Ai,
                                float* __restrict__ Ac) {
    int idx = blockIdx.x * 256 + threadIdx.x;
    if (idx >= G64 * 2048) return;
    int chunk = idx >> 11, rem = idx & 2047;
    int q = rem >> 8, rem2 = rem & 255;
    int l = rem2 >> 2, j = rem2 & 3;
    int g = chunk * 64 + l;
    int k = 2 * q + (j >> 1);
    float v = 0.f;
    if (g < Gg && k < Nn) v = (j & 1) ? Ai[k * Gg + g] : Ar[k * Gg + g];
    Ac[idx] = v;
}

__device__ __forceinline__ float a_elem(const float* __restrict__ Ar,
                                        const float* __restrict__ Ai,
                                        int n, int g2) {
    if (g2 < Gg) {
        return (n < Nn) ? Ar[n * Gg + g2] : Ai[(n - Nn) * Gg + g2];
    } else {
        int g = g2 - Gg;
        return (n < Nn) ? -Ai[n * Gg + g] : Ar[(n - Nn) * Gg + g];
    }
}

// M30[i][j] = sum_g2 A[i][g2]*A[j][g2]  (double accumulation), coalesced over g2
__global__ void gram_kernel(const float* __restrict__ Ar, const float* __restrict__ Ai,
                            double* __restrict__ M30) {
    int i = blockIdx.x / NNc, j = blockIdx.x % NNc;
    double acc = 0.0;
    for (int g2 = threadIdx.x; g2 < G2c; g2 += 256)
        acc += (double)a_elem(Ar, Ai, i, g2) * (double)a_elem(Ar, Ai, j, g2);
    __shared__ double red[256];
    red[threadIdx.x] = acc;
    __syncthreads();
    for (int s = 128; s > 0; s >>= 1) {
        if (threadIdx.x < s) red[threadIdx.x] += red[threadIdx.x + s];
        __syncthreads();
    }
    if (threadIdx.x == 0) M30[i * NNc + j] = red[0];
}

// Largest eigenvalue of the 30x30 Gram via 10 LDS matrix squarings (M^1024),
// dominant eigvec = column 0, then Rayleigh with original M. fp64, 1024 threads.
__global__ void step_kernel(const double* __restrict__ M30, float* __restrict__ st) {
    __shared__ double M0[NNc][NNc];
    __shared__ double Mc[NNc][NNc];
    __shared__ double s[1024];
    int tid = threadIdx.x;
    int i = tid / NNc, j = tid - i * NNc;
    bool act = tid < NNc * NNc;
    if (act) M0[i][j] = M30[tid];
    __syncthreads();
    s[tid] = act ? fabs(M0[i][j]) : 0.0;
    __syncthreads();
    for (int o = 512; o; o >>= 1) {
        if (tid < o) s[tid] = fmax(s[tid], s[tid + o]);
        __syncthreads();
    }
    double mx = s[0];
    __syncthreads();
    if (act) Mc[i][j] = M0[i][j] / mx;
    __syncthreads();
    for (int sq = 0; sq < 10; sq++) {
        double t = 0.0;
        if (act) {
            for (int k = 0; k < NNc; k++) t += Mc[i][k] * Mc[k][j];
        }
        s[tid] = act ? fabs(t) : 0.0;
        __syncthreads();
        for (int o = 512; o; o >>= 1) {
            if (tid < o) s[tid] = fmax(s[tid], s[tid + o]);
            __syncthreads();
        }
        double m2 = s[0];
        __syncthreads();
        if (act) Mc[i][j] = t / m2;
        __syncthreads();
    }
    s[tid] = act ? Mc[i][0] * M0[i][j] * Mc[j][0] : 0.0;
    __syncthreads();
    for (int o = 512; o; o >>= 1) {
        if (tid < o) s[tid] += s[tid + o];
        __syncthreads();
    }
    double num = s[0];
    __syncthreads();
    s[tid] = (tid < NNc) ? Mc[tid][0] * Mc[tid][0] : 0.0;
    __syncthreads();
    for (int o = 512; o; o >>= 1) {
        if (tid < o) s[tid] += s[tid + o];
        __syncthreads();
    }
    double den = s[0];
    if (tid == 0) {
        double lam = num / den;              // sigma_max(A)^2
        double step = (double)NNc / lam;     // 1 / (lam/30)
        st[0] = (float)step;
        st[1] = (float)(0.01 * step);        // MU * step
        st[2] = (float)(step / 30.0);        // folded scale for Aty and Ax
    }
}

// Packed Aty: AtyP[((b4*2 + s)*GP + g)] is a float4 =
//   (re(col 4*b4+2s), im(col 4*b4+2s), re(col 4*b4+2s+1), im(col 4*b4+2s+1)),
// scaled by step/30. Unit-stride in g for each set.
__global__ void atys_kernel(const float* __restrict__ Ar, const float* __restrict__ Ai,
                            const float* __restrict__ yr, const float* __restrict__ yi,
                            const float* __restrict__ st, float* __restrict__ AtyP) {
    int bt = blockIdx.x;
    int b = bt / Tt, t = bt - b * Tt;
    int b4 = bt >> 2, c = bt & 3, s = c >> 1, half = c & 1;
    __shared__ float ysr[Nn], ysi[Nn];
    int tid = threadIdx.x;
    if (tid < Nn) {
        float s2 = st[2];
        ysr[tid] = s2 * yr[(b * Nn + tid) * Tt + t];
        ysi[tid] = s2 * yi[(b * Nn + tid) * Tt + t];
    }
    __syncthreads();
    float* base = AtyP + (((size_t)(b4 * 2 + s)) * GP) * 4 + half * 2;
    for (int g = tid; g < GP; g += 256) {
        float accR = 0.f, accI = 0.f;
        if (g < Gg) {
#pragma unroll
            for (int k = 0; k < Nn; k++) {
                float a = Ar[k * Gg + g], ci = Ai[k * Gg + g];
                accR = fmaf(a, ysr[k], accR);
                accR = fmaf(ci, ysi[k], accR);
                accI = fmaf(-ci, ysr[k], accI);
                accI = fmaf(a, ysi[k], accI);
            }
        }
        float2* p = (float2*)(base + (size_t)g * 4);
        *p = make_float2(accR, accI);
    }
}

// ---------------- fused ISTA solver ----------------
// Round-6 verified configuration: block owns 4 columns; 2 sets x 256 threads,
// each set owns 2 columns. Per step a thread loads 8 float4 of packed A
// (covering all 30 rows of grid point g) + 1 float4 of packed Aty, updates
// both columns. __launch_bounds__(512,2) -> 128 VGPR, no spills (verified).
__global__ __launch_bounds__(TPB, 2) void ista_kernel(
    const float4* __restrict__ Ac4, const float4* __restrict__ AtyP4,
    const float* __restrict__ st, float* __restrict__ Xg,
    float* __restrict__ norms_g) {
    __shared__ float Xli[CPB][GP * 2];   // 155,648 B, [c][g][re,im]
    __shared__ float red[8][64];
    __shared__ float axb[CPB][32];
    int tid = threadIdx.x;
    int sset = tid >> 8;          // 0/1
    int l256 = tid & 255;
    int wsub = (tid >> 6) & 3;    // wave within set, 0..3
    int lane = tid & 63;
    int wv = tid >> 6;            // wave 0..7
    int c0 = 2 * sset, c1 = c0 + 1;
    int b4 = blockIdx.x;
    float thr = st[1], st2 = st[2];

    for (int k = tid; k < CPB * GP * 2; k += TPB) ((float*)Xli)[k] = 0.f;
    if (tid < CPB * 32) ((float*)axb)[tid] = 0.f;
    __syncthreads();

    const float4* atyp = AtyP4 + (size_t)(b4 * 2 + sset) * GP;

    for (int it = 0; it < NITER; it++) {
        float ax0[NNc], ax1[NNc];
#pragma unroll
        for (int n = 0; n < NNc; n++) { ax0[n] = axb[c0][n]; ax1[n] = axb[c1][n]; }
        float aR0[Nn], aI0[Nn], aR1[Nn], aI1[Nn];
#pragma unroll
        for (int k = 0; k < Nn; k++) { aR0[k] = 0.f; aI0[k] = 0.f; aR1[k] = 0.f; aI1[k] = 0.f; }

        for (int stp = 0; stp < 19; stp++) {
            int g = stp * 256 + l256;
            int chunk = (stp << 2) + wsub;
            const float4* pA = Ac4 + (size_t)chunk * 512 + lane;
            float4 aq[8];
#pragma unroll
            for (int q = 0; q < 8; q++) aq[q] = pA[q * 64];
            float4 ty = atyp[g];
            float2 x0 = *(const float2*)(&Xli[c0][2 * g]);
            float2 x1 = *(const float2*)(&Xli[c1][2 * g]);
            // v = x + step*Aty - step/30 * A^T(Ax)
            float vr0 = x0.x + ty.x, vi0 = x0.y + ty.y;
            float vr1 = x1.x + ty.z, vi1 = x1.y + ty.w;
#pragma unroll
            for (int q = 0; q < 7; q++) {
                float4 a = aq[q];
                int k0 = 2 * q, k1 = 2 * q + 1;
                vr0 = fmaf(-a.x, ax0[k0], vr0); vr0 = fmaf(-a.y, ax0[Nn + k0], vr0);
                vi0 = fmaf( a.y, ax0[k0], vi0); vi0 = fmaf(-a.x, ax0[Nn + k0], vi0);
                vr0 = fmaf(-a.z, ax0[k1], vr0); vr0 = fmaf(-a.w, ax0[Nn + k1], vr0);
                vi0 = fmaf( a.w, ax0[k1], vi0); vi0 = fmaf(-a.z, ax0[Nn + k1], vi0);
                vr1 = fmaf(-a.x, ax1[k0], vr1); vr1 = fmaf(-a.y, ax1[Nn + k0], vr1);
                vi1 = fmaf( a.y, ax1[k0], vi1); vi1 = fmaf(-a.x, ax1[Nn + k0], vi1);
                vr1 = fmaf(-a.z, ax1[k1], vr1); vr1 = fmaf(-a.w, ax1[Nn + k1], vr1);
                vi1 = fmaf( a.w, ax1[k1], vi1); vi1 = fmaf(-a.z, ax1[Nn + k1], vi1);
            }
            {   // tail k = 14 (aq[7].x/.y; .z/.w are zero pad)
                float4 a = aq[7];
                vr0 = fmaf(-a.x, ax0[14], vr0); vr0 = fmaf(-a.y, ax0[29], vr0);
                vi0 = fmaf( a.y, ax0[14], vi0); vi0 = fmaf(-a.x, ax0[29], vi0);
                vr1 = fmaf(-a.x, ax1[14], vr1); vr1 = fmaf(-a.y, ax1[29], vr1);
                vi1 = fmaf( a.y, ax1[14], vi1); vi1 = fmaf(-a.x, ax1[29], vi1);
            }
            float m;
            m = fabsf(vr0) - thr; float xr0 = (m > 0.f) ? copysignf(m, vr0) : 0.f;
            m = fabsf(vi0) - thr; float xi0 = (m > 0.f) ? copysignf(m, vi0) : 0.f;
            m = fabsf(vr1) - thr; float xr1 = (m > 0.f) ? copysignf(m, vr1) : 0.f;
            m = fabsf(vi1) - thr; float xi1 = (m > 0.f) ? copysignf(m, vi1) : 0.f;
            *(float2*)(&Xli[c0][2 * g]) = make_float2(xr0, xi0);
            *(float2*)(&Xli[c1][2 * g]) = make_float2(xr1, xi1);
            // sparse accumulation: skip waves whose 64 g's are all-zero (exact)
            int nz = (xr0 != 0.f) | (xi0 != 0.f) | (xr1 != 0.f) | (xi1 != 0.f);
            if (__any(nz)) {
#pragma unroll
                for (int q = 0; q < 7; q++) {
                    float4 a = aq[q];
                    int k0 = 2 * q, k1 = 2 * q + 1;
                    aR0[k0] = fmaf(a.x, xr0, aR0[k0]); aR0[k0] = fmaf(-a.y, xi0, aR0[k0]);
                    aI0[k0] = fmaf(a.y, xr0, aI0[k0]); aI0[k0] = fmaf( a.x, xi0, aI0[k0]);
                    aR0[k1] = fmaf(a.z, xr0, aR0[k1]); aR0[k1] = fmaf(-a.w, xi0, aR0[k1]);
                    aI0[k1] = fmaf(a.w, xr0, aI0[k1]); aI0[k1] = fmaf( a.z, xi0, aI0[k1]);
                    aR1[k0] = fmaf(a.x, xr1, aR1[k0]); aR1[k0] = fmaf(-a.y, xi1, aR1[k0]);
                    aI1[k0] = fmaf(a.y, xr1, aI1[k0]); aI1[k0] = fmaf( a.x, xi1, aI1[k0]);
                    aR1[k1] = fmaf(a.z, xr1, aR1[k1]); aR1[k1] = fmaf(-a.w, xi1, aR1[k1]);
                    aI1[k1] = fmaf(a.w, xr1, aI1[k1]); aI1[k1] = fmaf( a.z, xi1, aI1[k1]);
                }
                {
                    float4 a = aq[7];
                    aR0[14] = fmaf(a.x, xr0, aR0[14]); aR0[14] = fmaf(-a.y, xi0, aR0[14]);
                    aI0[14] = fmaf(a.y, xr0, aI0[14]); aI0[14] = fmaf( a.x, xi0, aI0[14]);
                    aR1[14] = fmaf(a.x, xr1, aR1[14]); aR1[14] = fmaf(-a.y, xi1, aR1[14]);
                    aI1[14] = fmaf(a.y, xr1, aI1[14]); aI1[14] = fmaf( a.x, xi1, aI1[14]);
                }
            }
        }
        if (it == NITER - 1) break;
        // wave-level butterfly reduce of the 60 accumulators
#pragma unroll
        for (int k = 0; k < Nn; k++) {
            for (int o = 32; o; o >>= 1) {
                aR0[k] += __shfl_xor(aR0[k], o);
                aI0[k] += __shfl_xor(aI0[k], o);
                aR1[k] += __shfl_xor(aR1[k], o);
                aI1[k] += __shfl_xor(aI1[k], o);
            }
        }
        if (lane == 0) {
#pragma unroll
            for (int k = 0; k < Nn; k++) {
                red[wv][k] = aR0[k];
                red[wv][Nn + k] = aI0[k];
                red[wv][30 + k] = aR1[k];
                red[wv][45 + k] = aI1[k];
            }
        }
        __syncthreads();
        if (tid < CPB * NNc) {
            int c = tid / NNc, n = tid - c * NNc;
            int s4 = (c >> 1) * 4, off = (c & 1) * 30 + n;
            axb[c][n] = st2 * (red[s4][off] + red[s4 + 1][off] +
                               red[s4 + 2][off] + red[s4 + 3][off]);
        }
        __syncthreads();
    }
    __syncthreads();

    // writeback X (layout Xg[bt][G2c]: real at g, imag at Gg+g) + column norms
    for (int c = 0; c < CPB; c++) {
        int bt = b4 * CPB + c;
        float na = 0.f;
        for (int g = tid; g < Gg; g += TPB) {
            float2 xv = *(const float2*)(&Xli[c][2 * g]);
            Xg[(size_t)bt * G2c + g] = xv.x;
            Xg[(size_t)bt * G2c + Gg + g] = xv.y;
            na += sqrtf(fmaf(xv.x, xv.x, fmaf(xv.y, xv.y, 1e-12f)));
        }
        for (int o = 32; o; o >>= 1) na += __shfl_xor(na, o);
        if (lane == 0) red[wv][c] = na;
    }
    __syncthreads();
    if (tid < CPB) {
        float s = 0.f;
        for (int w = 0; w < 8; w++) s += red[w][tid];
        norms_g[b4 * CPB + tid] = s;
    }
}

// ---------------- epilogue kernels ----------------

__global__ __launch_bounds__(832) void argmin_kernel(const float* __restrict__ norms_g,
                                                     int* __restrict__ midx) {
    __shared__ float norms[BTc];
    int tid = threadIdx.x;
    if (tid < BTc) norms[tid] = norms_g[tid];
    __syncthreads();
    if (tid < Bb) {
        float best = norms[tid * Tt];
        int bi = 0;
        for (int t = 1; t < Tt; t++) {
            float v = norms[tid * Tt + t];
            if (v < best) { best = v; bi = t; }
        }
        midx[tid] = bi;
    }
}

// s[b][g] = (1/16) * sum_j sqrt(x[g][b*50+tj]^2 + x[G+g][b*50+tj]^2 + 1e-12)
__global__ void s_kernel(const float* __restrict__ Xg, const int* __restrict__ midx,
                         float* __restrict__ out_s) {
    __shared__ int mi[Bb];
    if (threadIdx.x < Bb) mi[threadIdx.x] = midx[threadIdx.x];
    __syncthreads();
    int idx = blockIdx.x * 256 + threadIdx.x;
    if (idx >= Bb * Gg) return;
    int b = idx / Gg, g = idx - b * Gg;
    float acc = 0.f;
#pragma unroll
    for (int j = 0; j < Bb; j++) {
        int bt = b * Tt + mi[j];
        float xr = Xg[(size_t)bt * G2c + g];
        float xi = Xg[(size_t)bt * G2c + Gg + g];
        acc += sqrtf(fmaf(xr, xr, fmaf(xi, xi, 1e-12f)));
    }
    out_s[idx] = acc * (1.f / 16.f);
}

__device__ __forceinline__ bool better_pair(float v, int i, float bv, int bi) {
    return (v > bv) || (v == bv && i < bi);
}

// Stable top-2 per batch (lax.top_k semantics: descending, ties -> lower index)
__global__ void top2_kernel(const float* __restrict__ out_s, const float* __restrict__ angles,
                            const float* __restrict__ ranges, float* __restrict__ out) {
    int b = blockIdx.x, tid = threadIdx.x;
    const float* sb = out_s + (size_t)b * Gg;
    float v1 = -INFINITY, v2 = -INFINITY;
    int i1 = 0x7fffffff, i2 = 0x7fffffff;
    for (int g = tid; g < Gg; g += 256) {
        float v = sb[g];
        if (better_pair(v, g, v1, i1)) { v2 = v1; i2 = i1; v1 = v; i1 = g; }
        else if (better_pair(v, g, v2, i2)) { v2 = v; i2 = g; }
    }
    __shared__ float sv1[256], sv2[256];
    __shared__ int si1[256], si2[256];
    sv1[tid] = v1; si1[tid] = i1; sv2[tid] = v2; si2[tid] = i2;
    __syncthreads();
    for (int stp = 128; stp > 0; stp >>= 1) {
        if (tid < stp) {
            float a1 = sv1[tid], a2 = sv2[tid];
            int ai1 = si1[tid], ai2 = si2[tid];
            float b1 = sv1[tid + stp], b2 = sv2[tid + stp];
            int bi1 = si1[tid + stp], bi2 = si2[tid + stp];
            float n1, n2;
            int ni1, ni2;
            if (better_pair(b1, bi1, a1, ai1)) {
                n1 = b1; ni1 = bi1;
                if (better_pair(a1, ai1, b2, bi2)) { n2 = a1; ni2 = ai1; }
                else { n2 = b2; ni2 = bi2; }
            } else {
                n1 = a1; ni1 = ai1;
                if (better_pair(b1, bi1, a2, ai2)) { n2 = b1; ni2 = bi1; }
                else { n2 = a2; ni2 = ai2; }
            }
            sv1[tid] = n1; si1[tid] = ni1; sv2[tid] = n2; si2[tid] = ni2;
        }
        __syncthreads();
    }
    if (tid == 0) {
        int ia = si1[0], ib2 = si2[0];
        out[b * 2 + 0] = angles[ia / NRANGES];
        out[b * 2 + 1] = angles[ib2 / NRANGES];
        out[32 + b * 2 + 0] = ranges[ia % NRANGES];
        out[32 + b * 2 + 1] = ranges[ib2 % NRANGES];
    }
}

// ---------------- launch ----------------

extern "C" void kernel_launch(void* const* d_in, const int* in_sizes, int n_in,
                              void* d_out, int out_size, void* d_ws, size_t ws_size,
                              hipStream_t stream) {
    const float* yr = (const float*)d_in[0];      // [16,15,50]
    const float* yi = (const float*)d_in[1];      // [16,15,50]
    const float* Ar = (const float*)d_in[2];      // [15,4840]
    const float* Ai = (const float*)d_in[3];      // [15,4840]
    const float* angles = (const float*)d_in[4];  // [121]
    const float* ranges = (const float*)d_in[5];  // [40]
    float* out = (float*)d_out;                   // 32 doa + 32 rng + 77440 s
    float* w = (float*)d_ws;

    // workspace layout (floats), ~63 MB total; all float4 users 16B-aligned
    size_t oAc = 0;                                // 76*2048 = 155648
    size_t oM30 = oAc + (size_t)G64 * 2048;        // 900 doubles
    size_t oSt = oM30 + 1800;                      // 8
    size_t oAtyP = oSt + 8;                        // 200*2*4864*4 = 7782400 (ofs 157456, 16B-aligned)
    size_t oXg = oAtyP + (size_t)NB * 2 * GP * 4;  // 800*9680 = 7744000
    size_t oNrm = oXg + (size_t)BTc * G2c;         // 800
    size_t oMidx = oNrm + BTc;                     // 16 ints

    float* Ac = w + oAc;
    double* M30 = (double*)(w + oM30);
    float* st = w + oSt;
    float* AtyP = w + oAtyP;
    float* Xg = w + oXg;
    float* norms_g = w + oNrm;
    int* midx = (int*)(w + oMidx);

    repack_a_kernel<<<(G64 * 2048) / 256, 256, 0, stream>>>(Ar, Ai, Ac);
    gram_kernel<<<NNc * NNc, 256, 0, stream>>>(Ar, Ai, M30);
    step_kernel<<<1, 1024, 0, stream>>>(M30, st);
    atys_kernel<<<BTc, 256, 0, stream>>>(Ar, Ai, yr, yi, st, AtyP);

    ista_kernel<<<NB, TPB, 0, stream>>>((const float4*)Ac, (const float4*)AtyP,
                                        st, Xg, norms_g);

    argmin_kernel<<<1, 832, 0, stream>>>(norms_g, midx);
    s_kernel<<<(Bb * Gg + 255) / 256, 256, 0, stream>>>(Xg, midx, out + 64);
    top2_kernel<<<Bb, 256, 0, stream>>>(out + 64, angles, ranges, out);
}